// Round 1
// baseline (122.969 us; speedup 1.0000x reference)
//
#include <hip/hip_runtime.h>
#include <math.h>

#define DM 256   // d_model
#define NP 256   // n == m == 256 points
#define NH 4     // heads
#define DH 64    // dim per head
#define PI_F 3.14159265358979323846f

// ---------------------------------------------------------------------------
// Kernel A: Q/K/V pointwise conv (GEMM) + bias, written transposed to
// T[b][h][pt][d] (d contiguous) so downstream reads coalesce.
// channel c in [0,256): d = c>>2, h = c&3  (reshape(b, dim, h, n))
// ---------------------------------------------------------------------------
__global__ __launch_bounds__(256) void qkv_proj_kernel(
    const float* __restrict__ x, const float* __restrict__ src,
    const float* __restrict__ Wq, const float* __restrict__ bq,
    const float* __restrict__ Wk, const float* __restrict__ bk,
    const float* __restrict__ Wv, const float* __restrict__ bv,
    float* __restrict__ Qt, float* __restrict__ Kt, float* __restrict__ Vt)
{
  const int tile = blockIdx.x;      // 64 tiles: 8x8 grid of 32x32 tiles
  const int mat  = blockIdx.y;      // 0=q, 1=k, 2=v
  const int b    = blockIdx.z;
  const int tc = (tile >> 3) * 32;  // channel tile origin
  const int tp = (tile & 7) * 32;   // point tile origin
  const float* W    = (mat == 0) ? Wq : (mat == 1) ? Wk : Wv;
  const float* bias = (mat == 0) ? bq : (mat == 1) ? bk : bv;
  const float* X    = ((mat == 0) ? x : src) + (size_t)b * DM * NP;
  float* T          = ((mat == 0) ? Qt : (mat == 1) ? Kt : Vt) + (size_t)b * NH * NP * DH;

  __shared__ float Ws[32][33];
  __shared__ float Xs[32][33];
  const int ty = threadIdx.x >> 4;   // 0..15
  const int tx = threadIdx.x & 15;   // 0..15
  float acc00 = 0.f, acc01 = 0.f, acc10 = 0.f, acc11 = 0.f;
  for (int k0 = 0; k0 < DM; k0 += 32) {
    for (int i = threadIdx.x; i < 1024; i += 256) {
      int r = i >> 5, c = i & 31;
      Ws[r][c] = W[(size_t)(tc + r) * DM + (k0 + c)];
      Xs[r][c] = X[(size_t)(k0 + r) * NP + (tp + c)];
    }
    __syncthreads();
    #pragma unroll
    for (int kk = 0; kk < 32; ++kk) {
      float w0 = Ws[ty * 2 + 0][kk], w1 = Ws[ty * 2 + 1][kk];
      float x0 = Xs[kk][tx * 2 + 0], x1 = Xs[kk][tx * 2 + 1];
      acc00 += w0 * x0; acc01 += w0 * x1;
      acc10 += w1 * x0; acc11 += w1 * x1;
    }
    __syncthreads();
  }
  #pragma unroll
  for (int i = 0; i < 2; ++i) {
    #pragma unroll
    for (int j = 0; j < 2; ++j) {
      int c = tc + ty * 2 + i;
      int p = tp + tx * 2 + j;
      float v = ((i == 0) ? ((j == 0) ? acc00 : acc01)
                          : ((j == 0) ? acc10 : acc11)) + bias[c];
      // transpose into [h][p][d]
      T[((size_t)(c & 3) * NP + p) * DH + (c >> 2)] = v;
    }
  }
}

// ---------------------------------------------------------------------------
// Kernel B: scores (q.k / 8), top-k via iterative wave argmax, softmax.
// One 64-lane wave per (b,h,n) row; 4 waves per block.
// ---------------------------------------------------------------------------
__global__ __launch_bounds__(256) void score_topk_kernel(
    const float* __restrict__ Qt, const float* __restrict__ Kt,
    const int* __restrict__ kptr,
    int* __restrict__ idx_ws, float* __restrict__ probs_ws)
{
  const int wid  = threadIdx.x >> 6;   // wave in block 0..3
  const int lane = threadIdx.x & 63;
  const int row  = blockIdx.x * 4 + wid;   // (b*NH + h)*NP + n
  const int bh   = row >> 8;               // b*NH + h

  __shared__ float qs[4][DH];
  qs[wid][lane] = Qt[(size_t)row * DH + lane];
  __syncthreads();

  int kk = *kptr;
  if (kk > 64) kk = 64;
  if (kk < 1) kk = 1;

  const float* kbase = Kt + (size_t)bh * NP * DH;

  // scores for m = lane, lane+64, lane+128, lane+192
  float s[4];
  #pragma unroll
  for (int slot = 0; slot < 4; ++slot) {
    const int m = lane + slot * 64;
    const float4* k4 = (const float4*)(kbase + (size_t)m * DH);
    const float4* q4 = (const float4*)qs[wid];
    float acc = 0.f;
    #pragma unroll
    for (int dd = 0; dd < 16; ++dd) {
      float4 a = k4[dd], b = q4[dd];
      acc += a.x * b.x + a.y * b.y + a.z * b.z + a.w * b.w;
    }
    s[slot] = acc * 0.125f;   // / sqrt(64)
  }

  // iterative top-k: j-th extracted max ends up in lane j's registers
  float myv = 0.f; int mym = 0;
  for (int j = 0; j < kk; ++j) {
    float v = s[0]; int mi = lane;
    #pragma unroll
    for (int slot = 1; slot < 4; ++slot) {
      if (s[slot] > v) { v = s[slot]; mi = lane + slot * 64; }
    }
    #pragma unroll
    for (int off = 32; off; off >>= 1) {
      float ov = __shfl_xor(v, off);
      int   om = __shfl_xor(mi, off);
      if (ov > v || (ov == v && om < mi)) { v = ov; mi = om; }
    }
    if (lane == j) { myv = v; mym = mi; }
    if (lane == (mi & 63)) s[mi >> 6] = -INFINITY;  // remove selected
  }

  // softmax over the kk selected values (lane j holds j-th largest)
  float vmax = __shfl(myv, 0);
  float e = (lane < kk) ? expf(myv - vmax) : 0.f;
  float ssum = e;
  #pragma unroll
  for (int off = 32; off; off >>= 1) ssum += __shfl_xor(ssum, off);
  if (lane < kk) {
    probs_ws[(size_t)row * 64 + lane] = e / ssum;
    idx_ws[(size_t)row * 64 + lane]   = mym;
  }
}

// ---------------------------------------------------------------------------
// Kernel C: gather + 3D rotary + weighted sum.
// out[b,d,h,n] = sum_j p_j * ( val[b,d,h,m_j]*cos(rot) + rot_half(val)*sin(rot) )
// rot from lrf[b,m]^T (x_pos[b,m] - src_pos[b,n]); alpha for d%4<2, phi else.
// One wave per (b,h,n); lane = d.
// ---------------------------------------------------------------------------
__global__ __launch_bounds__(256) void gather_rot_kernel(
    const float* __restrict__ Vt,
    const float* __restrict__ x_pos, const float* __restrict__ src_pos,
    const float* __restrict__ lrf,
    const int* __restrict__ idx_ws, const float* __restrict__ probs_ws,
    const int* __restrict__ kptr,
    float* __restrict__ O)
{
  const int wid  = threadIdx.x >> 6;
  const int lane = threadIdx.x & 63;
  const int row  = blockIdx.x * 4 + wid;  // (b*NH+h)*NP + n
  const int n    = row & (NP - 1);
  const int bh   = row >> 8;
  const int b    = bh >> 2;
  const int h    = bh & 3;

  int kk = *kptr;
  if (kk > 64) kk = 64;
  if (kk < 1) kk = 1;

  __shared__ int   ms[4][64];
  __shared__ float fca[4][64], fsa[4][64], fcp[4][64], fsp[4][64];

  if (lane < kk) {
    const int   m = idx_ws[(size_t)row * 64 + lane];
    const float p = probs_ws[(size_t)row * 64 + lane];
    const float* xp = x_pos  + ((size_t)b * NP + m) * 3;
    const float* sp = src_pos + ((size_t)b * NP + n) * 3;
    const float* L  = lrf    + ((size_t)b * NP + m) * 9;  // row-major [y][x]
    float r0 = xp[0] - sp[0], r1 = xp[1] - sp[1], r2 = xp[2] - sp[2];
    // posl_x = sum_y L[y][x] * r_y   (lrf^T r)
    float px = L[0] * r0 + L[3] * r1 + L[6] * r2;
    float py = L[1] * r0 + L[4] * r1 + L[7] * r2;
    float pz = L[2] * r0 + L[5] * r1 + L[8] * r2;
    float alpha = atanf(py / px);
    if (px < 0.f) alpha += PI_F;
    if (isnan(alpha)) alpha = 0.f;
    float phi = atanf(pz / sqrtf(px * px + py * py));
    if (isnan(phi)) phi = 0.f;
    float sa, ca, sph, cph;
    sincosf(alpha, &sa, &ca);
    sincosf(phi, &sph, &cph);
    ms [wid][lane] = m;
    fca[wid][lane] = p * ca;
    fsa[wid][lane] = p * sa;
    fcp[wid][lane] = p * cph;
    fsp[wid][lane] = p * sph;
  }
  __syncthreads();

  const float* vbase = Vt + (size_t)bh * NP * DH;
  const bool useA = ((lane & 3) < 2);   // d%4 in {0,1} -> alpha, else phi
  float acc = 0.f;
  for (int j = 0; j < kk; ++j) {
    const int m = ms[wid][j];
    const float v = vbase[(size_t)m * DH + lane];
    const float partner = __shfl_xor(v, 1);
    const float dsc = (lane & 1) ? partner : -partner;  // rotate-half
    const float pc = useA ? fca[wid][j] : fcp[wid][j];
    const float ps = useA ? fsa[wid][j] : fsp[wid][j];
    acc += v * pc + dsc * ps;
  }
  const int c = (lane << 2) | h;   // channel = d*4 + h
  O[((size_t)b * DM + c) * NP + n] = acc;
}

// ---------------------------------------------------------------------------
// Kernel D: final pointwise conv: out[b,co,n] = Wm @ O + bm
// ---------------------------------------------------------------------------
__global__ __launch_bounds__(256) void final_proj_kernel(
    const float* __restrict__ O, const float* __restrict__ Wm,
    const float* __restrict__ bm, float* __restrict__ out)
{
  const int tile = blockIdx.x;
  const int b    = blockIdx.y;
  const int tc = (tile >> 3) * 32;
  const int tp = (tile & 7) * 32;
  const float* X = O + (size_t)b * DM * NP;
  float* Y       = out + (size_t)b * DM * NP;

  __shared__ float Ws[32][33];
  __shared__ float Xs[32][33];
  const int ty = threadIdx.x >> 4;
  const int tx = threadIdx.x & 15;
  float acc00 = 0.f, acc01 = 0.f, acc10 = 0.f, acc11 = 0.f;
  for (int k0 = 0; k0 < DM; k0 += 32) {
    for (int i = threadIdx.x; i < 1024; i += 256) {
      int r = i >> 5, c = i & 31;
      Ws[r][c] = Wm[(size_t)(tc + r) * DM + (k0 + c)];
      Xs[r][c] = X[(size_t)(k0 + r) * NP + (tp + c)];
    }
    __syncthreads();
    #pragma unroll
    for (int kk = 0; kk < 32; ++kk) {
      float w0 = Ws[ty * 2 + 0][kk], w1 = Ws[ty * 2 + 1][kk];
      float x0 = Xs[kk][tx * 2 + 0], x1 = Xs[kk][tx * 2 + 1];
      acc00 += w0 * x0; acc01 += w0 * x1;
      acc10 += w1 * x0; acc11 += w1 * x1;
    }
    __syncthreads();
  }
  #pragma unroll
  for (int i = 0; i < 2; ++i) {
    #pragma unroll
    for (int j = 0; j < 2; ++j) {
      int c = tc + ty * 2 + i;
      int p = tp + tx * 2 + j;
      float v = ((i == 0) ? ((j == 0) ? acc00 : acc01)
                          : ((j == 0) ? acc10 : acc11)) + bm[c];
      Y[(size_t)c * NP + p] = v;
    }
  }
}

// ---------------------------------------------------------------------------
extern "C" void kernel_launch(void* const* d_in, const int* in_sizes, int n_in,
                              void* d_out, int out_size, void* d_ws, size_t ws_size,
                              hipStream_t stream)
{
  const float* x       = (const float*)d_in[0];
  const float* source  = (const float*)d_in[1];
  const float* x_pos   = (const float*)d_in[2];
  const float* src_pos = (const float*)d_in[3];
  const float* lrf     = (const float*)d_in[4];
  const float* Wq = (const float*)d_in[5];
  const float* bq = (const float*)d_in[6];
  const float* Wk = (const float*)d_in[7];
  const float* bk = (const float*)d_in[8];
  const float* Wv = (const float*)d_in[9];
  const float* bv = (const float*)d_in[10];
  const float* Wm = (const float*)d_in[11];
  const float* bm = (const float*)d_in[12];
  const int* kptr = (const int*)d_in[13];
  float* out = (float*)d_out;

  // workspace layout (floats)
  float* ws = (float*)d_ws;
  float* Qt = ws;                         // [4][4][256][64] = 262144
  float* Kt = Qt + 262144;
  float* Vt = Kt + 262144;
  float* O  = Vt + 262144;                // [4][256][256]   = 262144
  int*   idx_ws   = (int*)(O + 262144);   // [4096][64]
  float* probs_ws = (float*)(idx_ws + 4096 * 64);
  // total: 6 MB

  qkv_proj_kernel<<<dim3(64, 3, 4), 256, 0, stream>>>(
      x, source, Wq, bq, Wk, bk, Wv, bv, Qt, Kt, Vt);
  score_topk_kernel<<<dim3(1024), 256, 0, stream>>>(
      Qt, Kt, kptr, idx_ws, probs_ws);
  gather_rot_kernel<<<dim3(1024), 256, 0, stream>>>(
      Vt, x_pos, src_pos, lrf, idx_ws, probs_ws, kptr, O);
  final_proj_kernel<<<dim3(64, 4), 256, 0, stream>>>(
      O, Wm, bm, out);
}

// Round 2
// 104.880 us; speedup vs baseline: 1.1725x; 1.1725x over previous
//
#include <hip/hip_runtime.h>
#include <math.h>

#define DM 256   // d_model
#define NP 256   // n == m == 256 points
#define NH 4     // heads
#define DH 64    // dim per head
#define PI_F 3.14159265358979323846f

// ---------------------------------------------------------------------------
// Kernel A: Q/K/V pointwise conv (GEMM) + bias, written transposed to
// T[b][h][pt][d] (d contiguous) so downstream reads coalesce.
// channel c in [0,256): d = c>>2, h = c&3  (reshape(b, dim, h, n))
// ---------------------------------------------------------------------------
__global__ __launch_bounds__(256) void qkv_proj_kernel(
    const float* __restrict__ x, const float* __restrict__ src,
    const float* __restrict__ Wq, const float* __restrict__ bq,
    const float* __restrict__ Wk, const float* __restrict__ bk,
    const float* __restrict__ Wv, const float* __restrict__ bv,
    float* __restrict__ Qt, float* __restrict__ Kt, float* __restrict__ Vt)
{
  const int tile = blockIdx.x;      // 64 tiles: 8x8 grid of 32x32 tiles
  const int mat  = blockIdx.y;      // 0=q, 1=k, 2=v
  const int b    = blockIdx.z;
  const int tc = (tile >> 3) * 32;  // channel tile origin
  const int tp = (tile & 7) * 32;   // point tile origin
  const float* W    = (mat == 0) ? Wq : (mat == 1) ? Wk : Wv;
  const float* bias = (mat == 0) ? bq : (mat == 1) ? bk : bv;
  const float* X    = ((mat == 0) ? x : src) + (size_t)b * DM * NP;
  float* T          = ((mat == 0) ? Qt : (mat == 1) ? Kt : Vt) + (size_t)b * NH * NP * DH;

  __shared__ float Ws[32][33];
  __shared__ float Xs[32][33];
  const int ty = threadIdx.x >> 4;   // 0..15
  const int tx = threadIdx.x & 15;   // 0..15
  float acc00 = 0.f, acc01 = 0.f, acc10 = 0.f, acc11 = 0.f;
  for (int k0 = 0; k0 < DM; k0 += 32) {
    for (int i = threadIdx.x; i < 1024; i += 256) {
      int r = i >> 5, c = i & 31;
      Ws[r][c] = W[(size_t)(tc + r) * DM + (k0 + c)];
      Xs[r][c] = X[(size_t)(k0 + r) * NP + (tp + c)];
    }
    __syncthreads();
    #pragma unroll
    for (int kk = 0; kk < 32; ++kk) {
      float w0 = Ws[ty * 2 + 0][kk], w1 = Ws[ty * 2 + 1][kk];
      float x0 = Xs[kk][tx * 2 + 0], x1 = Xs[kk][tx * 2 + 1];
      acc00 += w0 * x0; acc01 += w0 * x1;
      acc10 += w1 * x0; acc11 += w1 * x1;
    }
    __syncthreads();
  }
  #pragma unroll
  for (int i = 0; i < 2; ++i) {
    #pragma unroll
    for (int j = 0; j < 2; ++j) {
      int c = tc + ty * 2 + i;
      int p = tp + tx * 2 + j;
      float v = ((i == 0) ? ((j == 0) ? acc00 : acc01)
                          : ((j == 0) ? acc10 : acc11)) + bias[c];
      // transpose into [h][p][d]
      T[((size_t)(c & 3) * NP + p) * DH + (c >> 2)] = v;
    }
  }
}

// ---------------------------------------------------------------------------
// Kernel B (fused): scores -> rank-select top-k (counting, no serial argmax)
// -> softmax -> 3D-rotary gather-reduce. One 64-lane wave per (b,h,n) row.
//
// rank trick: 64-bit key = sortable(value)<<32 | (255-m). Keys are distinct,
// rank_i = #{key_j > key_i} is a permutation; selected iff rank < k and rank
// is the compaction slot. Pure VALU throughput (v_cmp_gt_u64 + addc), zero
// shuffles in selection.
// ---------------------------------------------------------------------------
__global__ __launch_bounds__(256) void attn_fused_kernel(
    const float* __restrict__ Qt, const float* __restrict__ Kt,
    const float* __restrict__ Vt,
    const float* __restrict__ x_pos, const float* __restrict__ src_pos,
    const float* __restrict__ lrf,
    const int* __restrict__ kptr,
    float* __restrict__ O)
{
  const int wid  = threadIdx.x >> 6;
  const int lane = threadIdx.x & 63;
  const int row  = blockIdx.x * 4 + wid;   // (b*NH + h)*NP + n
  const int n    = row & (NP - 1);
  const int bh   = row >> 8;
  const int b    = bh >> 2;
  const int h    = bh & 3;

  int kk = *kptr;
  if (kk > 64) kk = 64;
  if (kk < 1) kk = 1;

  __shared__ float qs[4][DH];                          // 1 KB
  __shared__ unsigned long long keys[4][NP];           // 8 KB
  __shared__ float sval[4][64];                        // 1 KB
  __shared__ int   sidx[4][64];                        // 1 KB
  __shared__ float4 ang[4][64];                        // 4 KB  {p*ca,p*sa,p*cph,p*sph}

  qs[wid][lane] = Qt[(size_t)row * DH + lane];
  __syncthreads();

  // ---- scores for m = lane + 64*slot --------------------------------------
  const float* kbase = Kt + (size_t)bh * NP * DH;
  const float4* q4 = (const float4*)qs[wid];
  const float4* kp0 = (const float4*)(kbase + ((size_t)lane      ) * DH);
  const float4* kp1 = (const float4*)(kbase + ((size_t)lane +  64) * DH);
  const float4* kp2 = (const float4*)(kbase + ((size_t)lane + 128) * DH);
  const float4* kp3 = (const float4*)(kbase + ((size_t)lane + 192) * DH);
  float s0 = 0.f, s1 = 0.f, s2 = 0.f, s3 = 0.f;
  #pragma unroll
  for (int dd = 0; dd < 16; ++dd) {
    float4 qv = q4[dd];
    float4 a0 = kp0[dd], a1 = kp1[dd], a2 = kp2[dd], a3 = kp3[dd];
    s0 += a0.x*qv.x + a0.y*qv.y + a0.z*qv.z + a0.w*qv.w;
    s1 += a1.x*qv.x + a1.y*qv.y + a1.z*qv.z + a1.w*qv.w;
    s2 += a2.x*qv.x + a2.y*qv.y + a2.z*qv.z + a2.w*qv.w;
    s3 += a3.x*qv.x + a3.y*qv.y + a3.z*qv.z + a3.w*qv.w;
  }
  float s[4] = { s0 * 0.125f, s1 * 0.125f, s2 * 0.125f, s3 * 0.125f };

  // ---- build sortable keys -------------------------------------------------
  unsigned long long mykey[4];
  #pragma unroll
  for (int slot = 0; slot < 4; ++slot) {
    unsigned int bits = __float_as_uint(s[slot]);
    unsigned int u = (bits & 0x80000000u) ? ~bits : (bits | 0x80000000u);
    int m = slot * 64 + lane;
    mykey[slot] = ((unsigned long long)u << 32) | (unsigned int)(255 - m);
    keys[wid][m] = mykey[slot];
  }
  __syncthreads();

  // ---- rank by counting (broadcast LDS reads, pure VALU) -------------------
  int rank[4] = {0, 0, 0, 0};
  const unsigned long long* kw = keys[wid];
  #pragma unroll 8
  for (int j2 = 0; j2 < NP; j2 += 2) {
    unsigned long long ka = kw[j2], kb = kw[j2 + 1];
    #pragma unroll
    for (int slot = 0; slot < 4; ++slot) {
      rank[slot] += (ka > mykey[slot]);
      rank[slot] += (kb > mykey[slot]);
    }
  }

  // ---- compaction: rank is a unique slot in [0,256) ------------------------
  #pragma unroll
  for (int slot = 0; slot < 4; ++slot) {
    if (rank[slot] < kk) {
      sval[wid][rank[slot]] = s[slot];
      sidx[wid][rank[slot]] = slot * 64 + lane;
    }
  }
  __syncthreads();

  // ---- softmax over selected + rotary angle coefficients -------------------
  float e = 0.f;
  int   msel = 0;
  if (lane < kk) {
    float v = sval[wid][lane];
    float vmax = sval[wid][0];          // rank 0 == global max
    e = expf(v - vmax);
    msel = sidx[wid][lane];
  }
  float ssum = e;
  #pragma unroll
  for (int off = 32; off; off >>= 1) ssum += __shfl_xor(ssum, off);

  if (lane < kk) {
    const float p = e / ssum;
    const float* xp = x_pos   + ((size_t)b * NP + msel) * 3;
    const float* sp = src_pos + ((size_t)b * NP + n) * 3;
    const float* L  = lrf     + ((size_t)b * NP + msel) * 9;  // row-major [y][x]
    float r0 = xp[0] - sp[0], r1 = xp[1] - sp[1], r2 = xp[2] - sp[2];
    float px = L[0]*r0 + L[3]*r1 + L[6]*r2;   // lrf^T r
    float py = L[1]*r0 + L[4]*r1 + L[7]*r2;
    float pz = L[2]*r0 + L[5]*r1 + L[8]*r2;
    float alpha = atanf(py / px);
    if (px < 0.f) alpha += PI_F;
    if (isnan(alpha)) alpha = 0.f;
    float phi = atanf(pz / sqrtf(px*px + py*py));
    if (isnan(phi)) phi = 0.f;
    float sa, ca, sph, cph;
    sincosf(alpha, &sa, &ca);
    sincosf(phi, &sph, &cph);
    ang[wid][lane] = make_float4(p * ca, p * sa, p * cph, p * sph);
  }
  __syncthreads();

  // ---- gather + rotate-half + weighted sum (8-deep pipelined) --------------
  const float* vbase = Vt + (size_t)bh * NP * DH;
  const bool useA = ((lane & 3) < 2);       // d%4 in {0,1} -> alpha else phi
  const bool odd  = (lane & 1);
  const int  ev   = lane & ~1;
  const float4* angp = ang[wid];
  float acc = 0.f;

  int j = 0;
  for (; j + 8 <= kk; j += 8) {
    int4 ma = *(const int4*)&sidx[wid][j];
    int4 mb = *(const int4*)&sidx[wid][j + 4];
    int mloc[8] = { ma.x, ma.y, ma.z, ma.w, mb.x, mb.y, mb.z, mb.w };
    float2 vv[8];
    #pragma unroll
    for (int t = 0; t < 8; ++t)
      vv[t] = *(const float2*)(vbase + (size_t)mloc[t] * DH + ev);
    float4 aa[8];
    #pragma unroll
    for (int t = 0; t < 8; ++t) aa[t] = angp[j + t];
    #pragma unroll
    for (int t = 0; t < 8; ++t) {
      float vm  = odd ? vv[t].y :  vv[t].x;
      float dsc = odd ? vv[t].x : -vv[t].y;   // rotate-half pairs
      float pc  = useA ? aa[t].x : aa[t].z;
      float ps  = useA ? aa[t].y : aa[t].w;
      acc += vm * pc + dsc * ps;
    }
  }
  for (; j < kk; ++j) {
    int m = sidx[wid][j];
    float2 v2 = *(const float2*)(vbase + (size_t)m * DH + ev);
    float vm  = odd ? v2.y :  v2.x;
    float dsc = odd ? v2.x : -v2.y;
    float4 a  = angp[j];
    float pc  = useA ? a.x : a.z;
    float ps  = useA ? a.y : a.w;
    acc += vm * pc + dsc * ps;
  }

  const int c = (lane << 2) | h;   // channel = d*4 + h
  O[((size_t)b * DM + c) * NP + n] = acc;
}

// ---------------------------------------------------------------------------
// Kernel D: final pointwise conv: out[b,co,n] = Wm @ O + bm
// ---------------------------------------------------------------------------
__global__ __launch_bounds__(256) void final_proj_kernel(
    const float* __restrict__ O, const float* __restrict__ Wm,
    const float* __restrict__ bm, float* __restrict__ out)
{
  const int tile = blockIdx.x;
  const int b    = blockIdx.y;
  const int tc = (tile >> 3) * 32;
  const int tp = (tile & 7) * 32;
  const float* X = O + (size_t)b * DM * NP;
  float* Y       = out + (size_t)b * DM * NP;

  __shared__ float Ws[32][33];
  __shared__ float Xs[32][33];
  const int ty = threadIdx.x >> 4;
  const int tx = threadIdx.x & 15;
  float acc00 = 0.f, acc01 = 0.f, acc10 = 0.f, acc11 = 0.f;
  for (int k0 = 0; k0 < DM; k0 += 32) {
    for (int i = threadIdx.x; i < 1024; i += 256) {
      int r = i >> 5, c = i & 31;
      Ws[r][c] = Wm[(size_t)(tc + r) * DM + (k0 + c)];
      Xs[r][c] = X[(size_t)(k0 + r) * NP + (tp + c)];
    }
    __syncthreads();
    #pragma unroll
    for (int kk = 0; kk < 32; ++kk) {
      float w0 = Ws[ty * 2 + 0][kk], w1 = Ws[ty * 2 + 1][kk];
      float x0 = Xs[kk][tx * 2 + 0], x1 = Xs[kk][tx * 2 + 1];
      acc00 += w0 * x0; acc01 += w0 * x1;
      acc10 += w1 * x0; acc11 += w1 * x1;
    }
    __syncthreads();
  }
  #pragma unroll
  for (int i = 0; i < 2; ++i) {
    #pragma unroll
    for (int j = 0; j < 2; ++j) {
      int c = tc + ty * 2 + i;
      int p = tp + tx * 2 + j;
      float v = ((i == 0) ? ((j == 0) ? acc00 : acc01)
                          : ((j == 0) ? acc10 : acc11)) + bm[c];
      Y[(size_t)c * NP + p] = v;
    }
  }
}

// ---------------------------------------------------------------------------
extern "C" void kernel_launch(void* const* d_in, const int* in_sizes, int n_in,
                              void* d_out, int out_size, void* d_ws, size_t ws_size,
                              hipStream_t stream)
{
  const float* x       = (const float*)d_in[0];
  const float* source  = (const float*)d_in[1];
  const float* x_pos   = (const float*)d_in[2];
  const float* src_pos = (const float*)d_in[3];
  const float* lrf     = (const float*)d_in[4];
  const float* Wq = (const float*)d_in[5];
  const float* bq = (const float*)d_in[6];
  const float* Wk = (const float*)d_in[7];
  const float* bk = (const float*)d_in[8];
  const float* Wv = (const float*)d_in[9];
  const float* bv = (const float*)d_in[10];
  const float* Wm = (const float*)d_in[11];
  const float* bm = (const float*)d_in[12];
  const int* kptr = (const int*)d_in[13];
  float* out = (float*)d_out;

  // workspace layout (floats)
  float* ws = (float*)d_ws;
  float* Qt = ws;                         // [4][4][256][64] = 262144
  float* Kt = Qt + 262144;
  float* Vt = Kt + 262144;
  float* O  = Vt + 262144;                // [4][256][256]   = 262144
  // total: 4 MB

  qkv_proj_kernel<<<dim3(64, 3, 4), 256, 0, stream>>>(
      x, source, Wq, bq, Wk, bk, Wv, bv, Qt, Kt, Vt);
  attn_fused_kernel<<<dim3(1024), 256, 0, stream>>>(
      Qt, Kt, Vt, x_pos, src_pos, lrf, kptr, O);
  final_proj_kernel<<<dim3(64, 4), 256, 0, stream>>>(
      O, Wm, bm, out);
}